// Round 8
// baseline (2039.760 us; speedup 1.0000x reference)
//
#include <hip/hip_runtime.h>

#define B2 2
#define DEG 16
#define SLOPE 0.2f
#define MAGIC1 0x5A17C3B9u
#define MAGIC2 0xA3E15D27u

typedef __attribute__((ext_vector_type(8))) short short8;
typedef __attribute__((ext_vector_type(8))) unsigned short ushort8;
typedef __attribute__((ext_vector_type(4))) unsigned short ushort4v;
typedef __attribute__((ext_vector_type(4))) float f32x4;

__device__ inline unsigned short f2bf(float f) {
  union { float f; unsigned u; } v; v.f = f;
  unsigned r = v.u + 0x7fff + ((v.u >> 16) & 1);   // RNE
  return (unsigned short)(r >> 16);
}
__device__ inline float bf2f(unsigned short u) {
  union { unsigned u; float f; } c; c.u = ((unsigned)u) << 16;
  return c.f;
}

__device__ inline float wave_dot256(const float* __restrict__ a,
                                    const float* __restrict__ b, int lane) {
  float4 x = *(const float4*)(a + lane * 4);
  float4 y = *(const float4*)(b + lane * 4);
  float v = x.x * y.x + x.y * y.y + x.z * y.z + x.w * y.w;
  #pragma unroll
  for (int off = 32; off; off >>= 1) v += __shfl_down(v, off);
  return v;
}

// D1+D2 merged. Block-units 0..31: transpose Ws/Wv -> bf16 (consumed by the
// NEXT dispatch — no flag needed). Units 32..160: comb row-dots + consts;
// each flags an 8-byte magic pair when done (uniform poison fills cannot
// forge two distinct words; stale flags from a prior iteration are benign —
// the guarded combs are bit-identical across iterations since inputs are
// constant). All 1024 blocks then spin on the 129 flags and grid-stride the
// node prep (f32->bf16 + logits). __launch_bounds__(256,4): VGPR<=128,
// LDS 16.6KB -> 4 blocks/CU guaranteed -> all 1024 blocks co-resident ->
// deadlock-free regardless of dispatch order (G16).
__global__ __launch_bounds__(256, 4) void prep_all_k(
    const float* __restrict__ nodes, const float* __restrict__ Ws,
    const float* __restrict__ Wt, const float* __restrict__ Wv,
    const float* __restrict__ Wa, const float* __restrict__ bs,
    const float* __restrict__ bt,
    unsigned short* __restrict__ WsT, unsigned short* __restrict__ WvT,
    float* __restrict__ ws_comb, float* __restrict__ wt_comb,
    float* __restrict__ consts, unsigned short* __restrict__ nodes_bf,
    float* __restrict__ an_s, float* __restrict__ an_t,
    unsigned int* __restrict__ flags, int nrows) {
  __shared__ float tile[64][65];
  const int u = blockIdx.x;
  const int tix = threadIdx.x;
  const int lane = tix & 63;

  if (u < 161) {
    if (u < 32) {
      const float* src = (u & 16) ? Wv : Ws;
      unsigned short* dst = (u & 16) ? WvT : WsT;
      int rc = u & 15;
      int r0 = (rc >> 2) * 64, c0 = (rc & 3) * 64;
      int tr = tix >> 6, tc = tix & 63;
      #pragma unroll
      for (int i = 0; i < 16; ++i) {
        int r = tr * 16 + i;
        tile[r][tc] = src[(long)(r0 + r) * 256 + c0 + tc];
      }
      __syncthreads();
      #pragma unroll
      for (int i = 0; i < 16; ++i) {
        int r = tr * 16 + i;
        dst[(long)(c0 + r) * 256 + r0 + tc] = f2bf(tile[tc][r]);
      }
    } else {
      int wave = (u - 32) * 4 + (tix >> 6);
      if (wave < 514) {
        const float *vec, *wa;
        float* dst;
        if (wave < 256)       { vec = Ws + (long)wave * 256;         wa = Wa;       dst = ws_comb + wave; }
        else if (wave < 512)  { vec = Wt + (long)(wave - 256) * 256; wa = Wa + 256; dst = wt_comb + (wave - 256); }
        else if (wave == 512) { vec = bs; wa = Wa;       dst = consts; }
        else                  { vec = bt; wa = Wa + 256; dst = consts + 1; }
        float v = wave_dot256(vec, wa, lane);
        if (lane == 0) *dst = v;
      }
      __syncthreads();
      __threadfence();
      if (tix == 0) {
        __hip_atomic_store(&flags[(u - 32) * 2], MAGIC1,
                           __ATOMIC_RELEASE, __HIP_MEMORY_SCOPE_AGENT);
        __hip_atomic_store(&flags[(u - 32) * 2 + 1], MAGIC2,
                           __ATOMIC_RELEASE, __HIP_MEMORY_SCOPE_AGENT);
      }
    }
  }

  // wait for all 129 comb block-units
  if (tix == 0) {
    for (int b = 0; b < 129; ++b) {
      while (__hip_atomic_load(&flags[b * 2], __ATOMIC_ACQUIRE,
                               __HIP_MEMORY_SCOPE_AGENT) != MAGIC1 ||
             __hip_atomic_load(&flags[b * 2 + 1], __ATOMIC_ACQUIRE,
                               __HIP_MEMORY_SCOPE_AGENT) != MAGIC2) {
        __builtin_amdgcn_s_sleep(8);
      }
    }
  }
  __syncthreads();

  // node prep: f32->bf16 + per-row logits; grid-stride over row-groups
  int nP2 = (nrows + 3) >> 2;
  for (int g = u; g < nP2; g += gridDim.x) {
    int row = g * 4 + (tix >> 6);
    if (row < nrows) {
      const float4 a = *(const float4*)(nodes + (long)row * 256 + lane * 4);
      ushort4v p;
      p[0] = f2bf(a.x); p[1] = f2bf(a.y); p[2] = f2bf(a.z); p[3] = f2bf(a.w);
      *(ushort4v*)(nodes_bf + (long)row * 256 + lane * 4) = p;
      const float4 w1 = *(const float4*)(ws_comb + lane * 4);
      const float4 w2 = *(const float4*)(wt_comb + lane * 4);
      float vs = a.x * w1.x + a.y * w1.y + a.z * w1.z + a.w * w1.w;
      float vt = a.x * w2.x + a.y * w2.y + a.z * w2.z + a.w * w2.w;
      #pragma unroll
      for (int off = 32; off; off >>= 1) {
        vs += __shfl_down(vs, off);
        vt += __shfl_down(vt, off);
      }
      if (lane == 0) { an_s[row] = vs; an_t[row] = vt; }
    }
  }
}

// D3: merged MFMA GEMM, 128x128 tile, BK=64 (R2-exact, proven 128.9 config).
// Operand-swapped MFMA: lane holds 4 consecutive output cols -> 8B C stores.
__global__ __launch_bounds__(256, 2) void gemm_mfma_k(
    const unsigned short* __restrict__ Abf,
    const int* __restrict__ usrc, const int* __restrict__ utgt,
    const unsigned short* __restrict__ WsT, const unsigned short* __restrict__ WvT,
    const float* __restrict__ bs, const float* __restrict__ bv,
    unsigned short* __restrict__ sproj_bf, unsigned short* __restrict__ vals_bf,
    const float* __restrict__ an_s, const float* __restrict__ an_t,
    const int* __restrict__ tid_arr, const float* __restrict__ consts,
    const float* __restrict__ ba, float* __restrict__ alpha,
    int Ms, int Mt, int Ns) {
  if (blockIdx.z == 2) {
    if (blockIdx.y != 0) return;
    int g = blockIdx.x * 256 + threadIdx.x;
    int s = g >> 1, b = g & 1;
    if (s >= Ns) return;
    float base = an_s[(long)usrc[s] * B2 + b] + consts[0] + consts[1] + ba[0];
    float ex[DEG];
    float den = 0.f;
    #pragma unroll
    for (int j = 0; j < DEG; ++j) {
      int t = tid_arr[s * DEG + j];
      float sc = base + an_t[(long)utgt[t] * B2 + b];
      sc = sc > 0.f ? sc : SLOPE * sc;
      sc = fminf(2.f, fmaxf(-2.f, sc));
      float ev = __expf(sc);
      ex[j] = ev;
      den += ev;
    }
    float inv = 1.f / den;
    #pragma unroll
    for (int j = 0; j < DEG; ++j) alpha[(long)(s * DEG + j) * B2 + b] = ex[j] * inv;
    return;
  }
  bool second = blockIdx.z != 0;
  const int* idx = second ? utgt : usrc;
  const unsigned short* WT = second ? WvT : WsT;
  const float* bias = second ? bv : bs;
  unsigned short* dstC = second ? vals_bf : sproj_bf;
  int M = second ? Mt : Ms;
  int row0 = blockIdx.x * 128, col0 = blockIdx.y * 128;
  if (row0 >= M) return;

  constexpr int LDT = 72;
  __shared__ unsigned short As[128 * LDT];
  __shared__ unsigned short Bs[128 * LDT];
  int t = threadIdx.x;
  int wv = t >> 6, lane = t & 63;
  int srow = t >> 3;           // 0..31
  int scol = (t & 7) * 8;      // 0..56
  const unsigned short* ap[4];
  #pragma unroll
  for (int p = 0; p < 4; ++p) {
    int m = row0 + srow + 32 * p;
    int mc = m < M ? m : M - 1;
    long ar = (long)idx[mc >> 1] * B2 + (mc & 1);
    ap[p] = Abf + ar * 256 + scol;
  }
  const unsigned short* bp[4];
  #pragma unroll
  for (int q = 0; q < 4; ++q)
    bp[q] = WT + (long)(col0 + srow + 32 * q) * 256 + scol;

  f32x4 acc[2][8];
  #pragma unroll
  for (int i = 0; i < 2; ++i)
    #pragma unroll
    for (int j = 0; j < 8; ++j) acc[i][j] = (f32x4)(0.f);

  // prologue loads for k0 = 0
  ushort8 av[4], bvv[4];
  #pragma unroll
  for (int p = 0; p < 4; ++p) av[p] = *(const ushort8*)(ap[p]);
  #pragma unroll
  for (int q = 0; q < 4; ++q) bvv[q] = *(const ushort8*)(bp[q]);

  #pragma unroll
  for (int k0 = 0; k0 < 256; k0 += 64) {
    __syncthreads();             // previous tile fully consumed
    #pragma unroll
    for (int p = 0; p < 4; ++p)
      *(ushort8*)&As[(srow + 32 * p) * LDT + scol] = av[p];
    #pragma unroll
    for (int q = 0; q < 4; ++q)
      *(ushort8*)&Bs[(srow + 32 * q) * LDT + scol] = bvv[q];
    __syncthreads();
    // prefetch next K-tile under the MFMAs
    if (k0 < 192) {
      #pragma unroll
      for (int p = 0; p < 4; ++p) av[p] = *(const ushort8*)(ap[p] + k0 + 64);
      #pragma unroll
      for (int q = 0; q < 4; ++q) bvv[q] = *(const ushort8*)(bp[q] + k0 + 64);
    }
    #pragma unroll
    for (int ks = 0; ks < 64; ks += 32) {
      int ko = ks + (lane >> 4) * 8;
      short8 af0 = *(const short8*)&As[(32 * wv + (lane & 15)) * LDT + ko];
      short8 af1 = *(const short8*)&As[(32 * wv + 16 + (lane & 15)) * LDT + ko];
      #pragma unroll
      for (int j = 0; j < 8; ++j) {
        short8 bf = *(const short8*)&Bs[(16 * j + (lane & 15)) * LDT + ko];
        acc[0][j] = __builtin_amdgcn_mfma_f32_16x16x32_bf16(bf, af0, acc[0][j], 0, 0, 0);
        acc[1][j] = __builtin_amdgcn_mfma_f32_16x16x32_bf16(bf, af1, acc[1][j], 0, 0, 0);
      }
    }
  }
  // Swapped-operand C/D mapping: lane l, reg q of acc[i][j] holds
  // C[row0+32wv+16i+(l&15)][col0+16j+4*(l>>4)+q] -> 4 consecutive cols.
  int cq = lane >> 4, rl = lane & 15;
  #pragma unroll
  for (int j = 0; j < 8; ++j) {
    int col = col0 + 16 * j + 4 * cq;
    float4 b4 = *(const float4*)(bias + col);
    #pragma unroll
    for (int i = 0; i < 2; ++i) {
      int row = row0 + 32 * wv + 16 * i + rl;
      if (row < M) {
        ushort4v p;
        p[0] = f2bf(acc[i][j][0] + b4.x);
        p[1] = f2bf(acc[i][j][1] + b4.y);
        p[2] = f2bf(acc[i][j][2] + b4.z);
        p[3] = f2bf(acc[i][j][3] + b4.w);
        *(ushort4v*)(dstC + (long)row * 256 + col) = p;
      }
    }
  }
}

// D4: ONE wave per source s covering both batch rows; pure store (no RMW).
// sproj/out are use-once streams -> nontemporal (protect reused vals in L2).
__global__ __launch_bounds__(256) void aggregate_k(
    const unsigned short* __restrict__ sproj, const unsigned short* __restrict__ vals,
    const float* __restrict__ alpha, const int* __restrict__ tid_arr,
    float* __restrict__ out, int Ns) {
  int s = blockIdx.x * 4 + (threadIdx.x >> 6);
  int lane = threadIdx.x & 63;
  if (s >= Ns) return;
  int f = tid_arr[s * DEG + (lane & 15)];   // edge id (reference quirk)
  int b = lane >> 5;
  float al = alpha[(long)f * B2 + b];       // alpha for (j=lane&15, b)
  int t2 = tid_arr[f];                      // value row = tid[tid[e]]
  ushort8 sp = __builtin_nontemporal_load(
      (const ushort8*)(sproj + (long)s * 512 + lane * 8));
  float acc[8];
  #pragma unroll
  for (int k = 0; k < 8; ++k) acc[k] = bf2f(sp[k]);
  #pragma unroll
  for (int j = 0; j < DEG; ++j) {
    int rr = __shfl(t2, j);
    float aj = __shfl(al, (lane & 32) + j);  // b-matched alpha for edge j
    ushort8 v = *(const ushort8*)(vals + (long)rr * 512 + lane * 8);
    #pragma unroll
    for (int k = 0; k < 8; ++k) acc[k] += aj * bf2f(v[k]);
  }
  long ob = (long)s * 512 + lane * 8;
  f32x4 p0, p1;
  p0[0] = acc[0]; p0[1] = acc[1]; p0[2] = acc[2]; p0[3] = acc[3];
  p1[0] = acc[4]; p1[1] = acc[5]; p1[2] = acc[6]; p1[3] = acc[7];
  __builtin_nontemporal_store(p0, (f32x4*)(out + ob));
  __builtin_nontemporal_store(p1, (f32x4*)(out + ob + 4));
}

extern "C" void kernel_launch(void* const* d_in, const int* in_sizes, int n_in,
                              void* d_out, int out_size, void* d_ws, size_t ws_size,
                              hipStream_t stream) {
  const float* nodes = (const float*)d_in[0];
  const float* Ws = (const float*)d_in[1];
  const float* bs = (const float*)d_in[2];
  const float* Wt = (const float*)d_in[3];
  const float* bt = (const float*)d_in[4];
  const float* Wv = (const float*)d_in[5];
  const float* bv = (const float*)d_in[6];
  const float* Wa = (const float*)d_in[7];
  const float* ba = (const float*)d_in[8];
  const int* usrc = (const int*)d_in[9];
  const int* utgt = (const int*)d_in[10];
  const int* tidp = (const int*)d_in[12];
  int Ns = in_sizes[9], Nt = in_sizes[10];
  int NsB = Ns * B2, NtB = Nt * B2;
  long nrows = in_sizes[0] / 256;   // N_NODES * B2

  unsigned short* nodes_bf = (unsigned short*)d_ws;        // nrows*256
  unsigned short* WsT = nodes_bf + nrows * 256;            // 65536
  unsigned short* WvT = WsT + 65536;                       // 65536
  unsigned short* vals_bf = WvT + 65536;                   // NtB*256
  unsigned short* sproj_bf = vals_bf + (size_t)NtB * 256;  // NsB*256
  float* fbase = (float*)(sproj_bf + (size_t)NsB * 256);
  float* an_s = fbase;                                     // nrows
  float* an_t = an_s + nrows;                              // nrows
  float* ws_comb = an_t + nrows;                           // 256
  float* wt_comb = ws_comb + 256;                          // 256
  float* consts = wt_comb + 256;                           // 2 (pad 16)
  float* alpha = consts + 16;                              // E*B2
  unsigned int* flags = (unsigned int*)(alpha + (size_t)Ns * DEG * B2);  // 258 u32
  float* out = (float*)d_out;

  prep_all_k<<<1024, 256, 0, stream>>>(
      nodes, Ws, Wt, Wv, Wa, bs, bt, WsT, WvT, ws_comb, wt_comb, consts,
      nodes_bf, an_s, an_t, flags, (int)nrows);
  int maxM = NsB > NtB ? NsB : NtB;
  gemm_mfma_k<<<dim3((maxM + 127) / 128, 2, 3), 256, 0, stream>>>(
      nodes_bf, usrc, utgt, WsT, WvT, bs, bv, sproj_bf, vals_bf,
      an_s, an_t, tidp, consts, ba, alpha, NsB, NtB, Ns);
  aggregate_k<<<(Ns + 3) / 4, 256, 0, stream>>>(
      sproj_bf, vals_bf, alpha, tidp, out, Ns);
}

// Round 9
// 149.637 us; speedup vs baseline: 13.6313x; 13.6313x over previous
//
#include <hip/hip_runtime.h>

#define B2 2
#define DEG 16
#define SLOPE 0.2f

typedef __attribute__((ext_vector_type(8))) short short8;
typedef __attribute__((ext_vector_type(8))) unsigned short ushort8;
typedef __attribute__((ext_vector_type(4))) unsigned short ushort4v;
typedef __attribute__((ext_vector_type(4))) float f32x4;

__device__ inline unsigned short f2bf(float f) {
  union { float f; unsigned u; } v; v.f = f;
  unsigned r = v.u + 0x7fff + ((v.u >> 16) & 1);   // RNE
  return (unsigned short)(r >> 16);
}
__device__ inline float bf2f(unsigned short u) {
  union { unsigned u; float f; } c; c.u = ((unsigned)u) << 16;
  return c.f;
}

__device__ inline float wave_dot256(const float* __restrict__ a,
                                    const float* __restrict__ b, int lane) {
  float4 x = *(const float4*)(a + lane * 4);
  float4 y = *(const float4*)(b + lane * 4);
  float v = x.x * y.x + x.y * y.y + x.z * y.z + x.w * y.w;
  #pragma unroll
  for (int off = 32; off; off >>= 1) v += __shfl_down(v, off);
  return v;
}

// K1 = D1+D2 merged WITHOUT handshake. Blocks 0..31: weight transpose
// (consumed only by K2 — next dispatch, safe). Blocks 32..: node prep; each
// block computes the 512 comb values REDUNDANTLY from Ws/Wt/Wa (per-thread
// 256-MAC dot; rows are L2-resident; ~512KB L2 reads per block), shares them
// via LDS, then grid-strides the node rows. No cross-block dependency (G16).
__global__ __launch_bounds__(256) void prep_k(
    const float* __restrict__ nodes, const float* __restrict__ Ws,
    const float* __restrict__ Wt, const float* __restrict__ Wv,
    const float* __restrict__ Wa,
    unsigned short* __restrict__ WsT, unsigned short* __restrict__ WvT,
    unsigned short* __restrict__ nodes_bf,
    float* __restrict__ an_s, float* __restrict__ an_t,
    int nrows, int npb) {
  const int u = blockIdx.x;
  const int tix = threadIdx.x;
  __shared__ float tile[64][65];
  __shared__ float cws[256], cwt[256];

  if (u < 32) {
    const float* src = (u & 16) ? Wv : Ws;
    unsigned short* dst = (u & 16) ? WvT : WsT;
    int rc = u & 15;
    int r0 = (rc >> 2) * 64, c0 = (rc & 3) * 64;
    int tr = tix >> 6, tc = tix & 63;
    #pragma unroll
    for (int i = 0; i < 16; ++i) {
      int r = tr * 16 + i;
      tile[r][tc] = src[(long)(r0 + r) * 256 + c0 + tc];
    }
    __syncthreads();
    #pragma unroll
    for (int i = 0; i < 16; ++i) {
      int r = tr * 16 + i;
      dst[(long)(c0 + r) * 256 + r0 + tc] = f2bf(tile[tc][r]);
    }
    return;
  }

  // per-block redundant comb: thread t owns comb index t
  {
    const float4* wa1 = (const float4*)Wa;          // Wa[0:256]
    const float4* wa2 = (const float4*)(Wa + 256);  // Wa[256:512]
    const float4* wsr = (const float4*)(Ws + (long)tix * 256);
    const float4* wtr = (const float4*)(Wt + (long)tix * 256);
    float4 s1 = make_float4(0.f, 0.f, 0.f, 0.f);
    float4 s2 = make_float4(0.f, 0.f, 0.f, 0.f);
    #pragma unroll 4
    for (int k = 0; k < 64; ++k) {
      float4 a = wsr[k], b = wa1[k];
      s1.x += a.x * b.x; s1.y += a.y * b.y;
      s1.z += a.z * b.z; s1.w += a.w * b.w;
      float4 c = wtr[k], d = wa2[k];
      s2.x += c.x * d.x; s2.y += c.y * d.y;
      s2.z += c.z * d.z; s2.w += c.w * d.w;
    }
    cws[tix] = (s1.x + s1.y) + (s1.z + s1.w);
    cwt[tix] = (s2.x + s2.y) + (s2.z + s2.w);
  }
  __syncthreads();

  const int lane = tix & 63;
  const float4 w1 = *(const float4*)&cws[lane * 4];
  const float4 w2 = *(const float4*)&cwt[lane * 4];
  int nP = (nrows + 3) >> 2;
  for (int g = u - 32; g < nP; g += npb) {
    int row = g * 4 + (tix >> 6);
    if (row < nrows) {
      const float4 a = *(const float4*)(nodes + (long)row * 256 + lane * 4);
      ushort4v p;
      p[0] = f2bf(a.x); p[1] = f2bf(a.y); p[2] = f2bf(a.z); p[3] = f2bf(a.w);
      *(ushort4v*)(nodes_bf + (long)row * 256 + lane * 4) = p;
      float vs = a.x * w1.x + a.y * w1.y + a.z * w1.z + a.w * w1.w;
      float vt = a.x * w2.x + a.y * w2.y + a.z * w2.z + a.w * w2.w;
      #pragma unroll
      for (int off = 32; off; off >>= 1) {
        vs += __shfl_down(vs, off);
        vt += __shfl_down(vt, off);
      }
      if (lane == 0) { an_s[row] = vs; an_t[row] = vt; }
    }
  }
}

// K2: merged MFMA GEMM (R2-exact structure, proven best). z=0: src_proj;
// z=1: vals; z=2 (y==0): alpha softmax — now computes the bias consts
// inline (two wave-dots + broadcast) instead of reading them from K1.
// Operand-swapped MFMA: lane holds 4 consecutive output cols -> 8B C stores.
__global__ __launch_bounds__(256, 2) void gemm_mfma_k(
    const unsigned short* __restrict__ Abf,
    const int* __restrict__ usrc, const int* __restrict__ utgt,
    const unsigned short* __restrict__ WsT, const unsigned short* __restrict__ WvT,
    const float* __restrict__ bs, const float* __restrict__ bv,
    const float* __restrict__ bt, const float* __restrict__ Wa,
    unsigned short* __restrict__ sproj_bf, unsigned short* __restrict__ vals_bf,
    const float* __restrict__ an_s, const float* __restrict__ an_t,
    const int* __restrict__ tid_arr,
    const float* __restrict__ ba, float* __restrict__ alpha,
    int Ms, int Mt, int Ns) {
  if (blockIdx.z == 2) {
    if (blockIdx.y != 0) return;
    int lane = threadIdx.x & 63;
    float c0 = wave_dot256(bs, Wa, lane);        c0 = __shfl(c0, 0);
    float c1 = wave_dot256(bt, Wa + 256, lane);  c1 = __shfl(c1, 0);
    int g = blockIdx.x * 256 + threadIdx.x;
    int s = g >> 1, b = g & 1;
    if (s >= Ns) return;
    float base = an_s[(long)usrc[s] * B2 + b] + c0 + c1 + ba[0];
    float ex[DEG];
    float den = 0.f;
    #pragma unroll
    for (int j = 0; j < DEG; ++j) {
      int t = tid_arr[s * DEG + j];
      float sc = base + an_t[(long)utgt[t] * B2 + b];
      sc = sc > 0.f ? sc : SLOPE * sc;
      sc = fminf(2.f, fmaxf(-2.f, sc));
      float ev = __expf(sc);
      ex[j] = ev;
      den += ev;
    }
    float inv = 1.f / den;
    #pragma unroll
    for (int j = 0; j < DEG; ++j) alpha[(long)(s * DEG + j) * B2 + b] = ex[j] * inv;
    return;
  }
  bool second = blockIdx.z != 0;
  const int* idx = second ? utgt : usrc;
  const unsigned short* WT = second ? WvT : WsT;
  const float* bias = second ? bv : bs;
  unsigned short* dstC = second ? vals_bf : sproj_bf;
  int M = second ? Mt : Ms;
  int row0 = blockIdx.x * 128, col0 = blockIdx.y * 128;
  if (row0 >= M) return;

  constexpr int LDT = 72;
  __shared__ unsigned short As[128 * LDT];
  __shared__ unsigned short Bs[128 * LDT];
  int t = threadIdx.x;
  int wv = t >> 6, lane = t & 63;
  int srow = t >> 3;           // 0..31
  int scol = (t & 7) * 8;      // 0..56
  const unsigned short* ap[4];
  #pragma unroll
  for (int p = 0; p < 4; ++p) {
    int m = row0 + srow + 32 * p;
    int mc = m < M ? m : M - 1;
    long ar = (long)idx[mc >> 1] * B2 + (mc & 1);
    ap[p] = Abf + ar * 256 + scol;
  }
  const unsigned short* bp[4];
  #pragma unroll
  for (int q = 0; q < 4; ++q)
    bp[q] = WT + (long)(col0 + srow + 32 * q) * 256 + scol;

  f32x4 acc[2][8];
  #pragma unroll
  for (int i = 0; i < 2; ++i)
    #pragma unroll
    for (int j = 0; j < 8; ++j) acc[i][j] = (f32x4)(0.f);

  // prologue loads for k0 = 0
  ushort8 av[4], bvv[4];
  #pragma unroll
  for (int p = 0; p < 4; ++p) av[p] = *(const ushort8*)(ap[p]);
  #pragma unroll
  for (int q = 0; q < 4; ++q) bvv[q] = *(const ushort8*)(bp[q]);

  #pragma unroll
  for (int k0 = 0; k0 < 256; k0 += 64) {
    __syncthreads();             // previous tile fully consumed
    #pragma unroll
    for (int p = 0; p < 4; ++p)
      *(ushort8*)&As[(srow + 32 * p) * LDT + scol] = av[p];
    #pragma unroll
    for (int q = 0; q < 4; ++q)
      *(ushort8*)&Bs[(srow + 32 * q) * LDT + scol] = bvv[q];
    __syncthreads();
    // prefetch next K-tile under the MFMAs
    if (k0 < 192) {
      #pragma unroll
      for (int p = 0; p < 4; ++p) av[p] = *(const ushort8*)(ap[p] + k0 + 64);
      #pragma unroll
      for (int q = 0; q < 4; ++q) bvv[q] = *(const ushort8*)(bp[q] + k0 + 64);
    }
    #pragma unroll
    for (int ks = 0; ks < 64; ks += 32) {
      int ko = ks + (lane >> 4) * 8;
      short8 af0 = *(const short8*)&As[(32 * wv + (lane & 15)) * LDT + ko];
      short8 af1 = *(const short8*)&As[(32 * wv + 16 + (lane & 15)) * LDT + ko];
      #pragma unroll
      for (int j = 0; j < 8; ++j) {
        short8 bf = *(const short8*)&Bs[(16 * j + (lane & 15)) * LDT + ko];
        acc[0][j] = __builtin_amdgcn_mfma_f32_16x16x32_bf16(bf, af0, acc[0][j], 0, 0, 0);
        acc[1][j] = __builtin_amdgcn_mfma_f32_16x16x32_bf16(bf, af1, acc[1][j], 0, 0, 0);
      }
    }
  }
  // Swapped-operand C/D mapping: lane l, reg q of acc[i][j] holds
  // C[row0+32wv+16i+(l&15)][col0+16j+4*(l>>4)+q] -> 4 consecutive cols.
  int cq = lane >> 4, rl = lane & 15;
  #pragma unroll
  for (int j = 0; j < 8; ++j) {
    int col = col0 + 16 * j + 4 * cq;
    float4 b4 = *(const float4*)(bias + col);
    #pragma unroll
    for (int i = 0; i < 2; ++i) {
      int row = row0 + 32 * wv + 16 * i + rl;
      if (row < M) {
        ushort4v p;
        p[0] = f2bf(acc[i][j][0] + b4.x);
        p[1] = f2bf(acc[i][j][1] + b4.y);
        p[2] = f2bf(acc[i][j][2] + b4.z);
        p[3] = f2bf(acc[i][j][3] + b4.w);
        *(ushort4v*)(dstC + (long)row * 256 + col) = p;
      }
    }
  }
}

// K3: ONE wave per source s covering both batch rows; pure store (no RMW).
// sproj/out are use-once streams -> nontemporal (protect reused vals in L2).
__global__ __launch_bounds__(256) void aggregate_k(
    const unsigned short* __restrict__ sproj, const unsigned short* __restrict__ vals,
    const float* __restrict__ alpha, const int* __restrict__ tid_arr,
    float* __restrict__ out, int Ns) {
  int s = blockIdx.x * 4 + (threadIdx.x >> 6);
  int lane = threadIdx.x & 63;
  if (s >= Ns) return;
  int f = tid_arr[s * DEG + (lane & 15)];   // edge id (reference quirk)
  int b = lane >> 5;
  float al = alpha[(long)f * B2 + b];       // alpha for (j=lane&15, b)
  int t2 = tid_arr[f];                      // value row = tid[tid[e]]
  ushort8 sp = __builtin_nontemporal_load(
      (const ushort8*)(sproj + (long)s * 512 + lane * 8));
  float acc[8];
  #pragma unroll
  for (int k = 0; k < 8; ++k) acc[k] = bf2f(sp[k]);
  #pragma unroll
  for (int j = 0; j < DEG; ++j) {
    int rr = __shfl(t2, j);
    float aj = __shfl(al, (lane & 32) + j);  // b-matched alpha for edge j
    ushort8 v = *(const ushort8*)(vals + (long)rr * 512 + lane * 8);
    #pragma unroll
    for (int k = 0; k < 8; ++k) acc[k] += aj * bf2f(v[k]);
  }
  long ob = (long)s * 512 + lane * 8;
  f32x4 p0, p1;
  p0[0] = acc[0]; p0[1] = acc[1]; p0[2] = acc[2]; p0[3] = acc[3];
  p1[0] = acc[4]; p1[1] = acc[5]; p1[2] = acc[6]; p1[3] = acc[7];
  __builtin_nontemporal_store(p0, (f32x4*)(out + ob));
  __builtin_nontemporal_store(p1, (f32x4*)(out + ob + 4));
}

extern "C" void kernel_launch(void* const* d_in, const int* in_sizes, int n_in,
                              void* d_out, int out_size, void* d_ws, size_t ws_size,
                              hipStream_t stream) {
  const float* nodes = (const float*)d_in[0];
  const float* Ws = (const float*)d_in[1];
  const float* bs = (const float*)d_in[2];
  const float* Wt = (const float*)d_in[3];
  const float* bt = (const float*)d_in[4];
  const float* Wv = (const float*)d_in[5];
  const float* bv = (const float*)d_in[6];
  const float* Wa = (const float*)d_in[7];
  const float* ba = (const float*)d_in[8];
  const int* usrc = (const int*)d_in[9];
  const int* utgt = (const int*)d_in[10];
  const int* tidp = (const int*)d_in[12];
  int Ns = in_sizes[9], Nt = in_sizes[10];
  int NsB = Ns * B2, NtB = Nt * B2;
  long nrows = in_sizes[0] / 256;   // N_NODES * B2

  unsigned short* nodes_bf = (unsigned short*)d_ws;        // nrows*256
  unsigned short* WsT = nodes_bf + nrows * 256;            // 65536
  unsigned short* WvT = WsT + 65536;                       // 65536
  unsigned short* vals_bf = WvT + 65536;                   // NtB*256
  unsigned short* sproj_bf = vals_bf + (size_t)NtB * 256;  // NsB*256
  float* fbase = (float*)(sproj_bf + (size_t)NsB * 256);
  float* an_s = fbase;                                     // nrows
  float* an_t = an_s + nrows;                              // nrows
  float* alpha = an_t + nrows;                             // E*B2
  float* out = (float*)d_out;

  const int NPB = 256;
  prep_k<<<32 + NPB, 256, 0, stream>>>(
      nodes, Ws, Wt, Wv, Wa, WsT, WvT, nodes_bf, an_s, an_t,
      (int)nrows, NPB);
  int maxM = NsB > NtB ? NsB : NtB;
  gemm_mfma_k<<<dim3((maxM + 127) / 128, 2, 3), 256, 0, stream>>>(
      nodes_bf, usrc, utgt, WsT, WvT, bs, bv, bt, Wa, sproj_bf, vals_bf,
      an_s, an_t, tidp, ba, alpha, NsB, NtB, Ns);
  aggregate_k<<<(Ns + 3) / 4, 256, 0, stream>>>(
      sproj_bf, vals_bf, alpha, tidp, out, Ns);
}

// Round 10
// 146.480 us; speedup vs baseline: 13.9252x; 1.0216x over previous
//
#include <hip/hip_runtime.h>

#define B2 2
#define DEG 16
#define SLOPE 0.2f

typedef __attribute__((ext_vector_type(8))) short short8;
typedef __attribute__((ext_vector_type(8))) unsigned short ushort8;
typedef __attribute__((ext_vector_type(4))) unsigned short ushort4v;
typedef __attribute__((ext_vector_type(4))) float f32x4;

__device__ inline unsigned short f2bf(float f) {
  union { float f; unsigned u; } v; v.f = f;
  unsigned r = v.u + 0x7fff + ((v.u >> 16) & 1);   // RNE
  return (unsigned short)(r >> 16);
}
__device__ inline float bf2f(unsigned short u) {
  union { unsigned u; float f; } c; c.u = ((unsigned)u) << 16;
  return c.f;
}
__device__ inline ushort8 f2bf8(float4 lo, float4 hi) {
  ushort8 r;
  r[0] = f2bf(lo.x); r[1] = f2bf(lo.y); r[2] = f2bf(lo.z); r[3] = f2bf(lo.w);
  r[4] = f2bf(hi.x); r[5] = f2bf(hi.y); r[6] = f2bf(hi.z); r[7] = f2bf(hi.w);
  return r;
}
__device__ inline float dot8(float4 a0, float4 a1, float4 c0, float4 c1) {
  return a0.x * c0.x + a0.y * c0.y + a0.z * c0.z + a0.w * c0.w +
         a1.x * c1.x + a1.y * c1.y + a1.z * c1.z + a1.w * c1.w;
}

__device__ inline float wave_dot256(const float* __restrict__ a,
                                    const float* __restrict__ b, int lane) {
  float4 x = *(const float4*)(a + lane * 4);
  float4 y = *(const float4*)(b + lane * 4);
  float v = x.x * y.x + x.y * y.y + x.z * y.z + x.w * y.w;
  #pragma unroll
  for (int off = 32; off; off >>= 1) v += __shfl_down(v, off);
  return v;
}

// K1: blocks 0..31 transpose Ws/Wv [K][N]f32 -> [N][K]bf16;
// blocks 32..160: ws_comb/wt_comb row-dots + consts. (R2-proven.)
__global__ __launch_bounds__(256) void prep_w_k(
    const float* __restrict__ Ws, const float* __restrict__ Wt,
    const float* __restrict__ Wv, const float* __restrict__ Wa,
    const float* __restrict__ bs, const float* __restrict__ bt,
    unsigned short* __restrict__ WsT, unsigned short* __restrict__ WvT,
    float* __restrict__ ws_comb, float* __restrict__ wt_comb,
    float* __restrict__ consts) {
  int bx = blockIdx.x;
  if (bx < 32) {
    const float* src = (bx & 16) ? Wv : Ws;
    unsigned short* dst = (bx & 16) ? WvT : WsT;
    int rc = bx & 15;
    int r0 = (rc >> 2) * 64, c0 = (rc & 3) * 64;
    __shared__ float tile[64][65];
    int tr = threadIdx.x >> 6, tc = threadIdx.x & 63;
    #pragma unroll
    for (int i = 0; i < 16; ++i) {
      int r = tr * 16 + i;
      tile[r][tc] = src[(long)(r0 + r) * 256 + c0 + tc];
    }
    __syncthreads();
    #pragma unroll
    for (int i = 0; i < 16; ++i) {
      int r = tr * 16 + i;
      dst[(long)(c0 + r) * 256 + r0 + tc] = f2bf(tile[tc][r]);
    }
  } else {
    int wave = (bx - 32) * 4 + (threadIdx.x >> 6);
    int lane = threadIdx.x & 63;
    if (wave >= 514) return;
    const float *vec, *wa;
    float* dst;
    if (wave < 256)       { vec = Ws + (long)wave * 256;         wa = Wa;       dst = ws_comb + wave; }
    else if (wave < 512)  { vec = Wt + (long)(wave - 256) * 256; wa = Wa + 256; dst = wt_comb + (wave - 256); }
    else if (wave == 512) { vec = bs; wa = Wa;       dst = consts; }
    else                  { vec = bt; wa = Wa + 256; dst = consts + 1; }
    float v = wave_dot256(vec, wa, lane);
    if (lane == 0) *dst = v;
  }
}

// K2: MFMA GEMM, 128x256 tile (BN=256: A staged ONCE), BK=64. A comes
// straight from f32 nodes (in-register RNE f2bf during staging — identical
// bits to the old nodes_bf path; D2 pass deleted). While staging, each
// thread also dots its A-strips with ws_comb/wt_comb -> an_s_m / an_t_m
// (per-GEMM-row logits), replacing D2's other output.
// Operand-swapped MFMA: lane holds 4 consecutive output cols -> 8B C stores.
__global__ __launch_bounds__(256, 2) void gemm_mfma_k(
    const float* __restrict__ nodesf,
    const int* __restrict__ usrc, const int* __restrict__ utgt,
    const unsigned short* __restrict__ WsT, const unsigned short* __restrict__ WvT,
    const float* __restrict__ bs, const float* __restrict__ bv,
    const float* __restrict__ ws_comb, const float* __restrict__ wt_comb,
    unsigned short* __restrict__ sproj_bf, unsigned short* __restrict__ vals_bf,
    float* __restrict__ an_s_m, float* __restrict__ an_t_m,
    int Ms, int Mt) {
  bool second = blockIdx.z != 0;
  const int* idx = second ? utgt : usrc;
  const unsigned short* WT = second ? WvT : WsT;
  const float* bias = second ? bv : bs;
  const float* comb = second ? wt_comb : ws_comb;
  unsigned short* dstC = second ? vals_bf : sproj_bf;
  float* anv = second ? an_t_m : an_s_m;
  int M = second ? Mt : Ms;
  int row0 = blockIdx.x * 128;
  if (row0 >= M) return;

  constexpr int LDT = 72;
  __shared__ unsigned short As[128 * LDT];
  __shared__ unsigned short Bs[256 * LDT];
  int t = threadIdx.x;
  int wv = t >> 6, lane = t & 63;
  int srow = t >> 3;           // 0..31
  int scol = (t & 7) * 8;      // 0..56
  const float* ap[4];
  #pragma unroll
  for (int p = 0; p < 4; ++p) {
    int m = row0 + srow + 32 * p;
    int mc = m < M ? m : M - 1;
    long ar = (long)idx[mc >> 1] * B2 + (mc & 1);
    ap[p] = nodesf + ar * 256 + scol;
  }
  const unsigned short* bp[8];
  #pragma unroll
  for (int q = 0; q < 8; ++q)
    bp[q] = WT + (long)(srow + 32 * q) * 256 + scol;

  f32x4 acc[2][16];
  #pragma unroll
  for (int i = 0; i < 2; ++i)
    #pragma unroll
    for (int j = 0; j < 16; ++j) acc[i][j] = (f32x4)(0.f);

  ushort8 avbf[4], bvv[8];
  float dp[4] = {0.f, 0.f, 0.f, 0.f};
  // prologue k0 = 0: load A (f32), dot with comb strip, convert to bf16
  {
    float4 c0 = *(const float4*)(comb + scol);
    float4 c1 = *(const float4*)(comb + scol + 4);
    #pragma unroll
    for (int p = 0; p < 4; ++p) {
      float4 a0 = *(const float4*)(ap[p]);
      float4 a1 = *(const float4*)(ap[p] + 4);
      dp[p] += dot8(a0, a1, c0, c1);
      avbf[p] = f2bf8(a0, a1);
    }
    #pragma unroll
    for (int q = 0; q < 8; ++q) bvv[q] = *(const ushort8*)(bp[q]);
  }

  #pragma unroll
  for (int k0 = 0; k0 < 256; k0 += 64) {
    __syncthreads();             // previous tile fully consumed
    #pragma unroll
    for (int p = 0; p < 4; ++p)
      *(ushort8*)&As[(srow + 32 * p) * LDT + scol] = avbf[p];
    #pragma unroll
    for (int q = 0; q < 8; ++q)
      *(ushort8*)&Bs[(srow + 32 * q) * LDT + scol] = bvv[q];
    __syncthreads();
    // prefetch next K-tile under the MFMAs (+ comb dot + convert)
    if (k0 < 192) {
      float4 c0 = *(const float4*)(comb + k0 + 64 + scol);
      float4 c1 = *(const float4*)(comb + k0 + 64 + scol + 4);
      #pragma unroll
      for (int p = 0; p < 4; ++p) {
        float4 a0 = *(const float4*)(ap[p] + k0 + 64);
        float4 a1 = *(const float4*)(ap[p] + k0 + 68);
        dp[p] += dot8(a0, a1, c0, c1);
        avbf[p] = f2bf8(a0, a1);
      }
      #pragma unroll
      for (int q = 0; q < 8; ++q) bvv[q] = *(const ushort8*)(bp[q] + k0 + 64);
    }
    #pragma unroll
    for (int ks = 0; ks < 64; ks += 32) {
      int ko = ks + (lane >> 4) * 8;
      short8 af0 = *(const short8*)&As[(32 * wv + (lane & 15)) * LDT + ko];
      short8 af1 = *(const short8*)&As[(32 * wv + 16 + (lane & 15)) * LDT + ko];
      #pragma unroll
      for (int j = 0; j < 16; ++j) {
        short8 bf = *(const short8*)&Bs[(16 * j + (lane & 15)) * LDT + ko];
        acc[0][j] = __builtin_amdgcn_mfma_f32_16x16x32_bf16(bf, af0, acc[0][j], 0, 0, 0);
        acc[1][j] = __builtin_amdgcn_mfma_f32_16x16x32_bf16(bf, af1, acc[1][j], 0, 0, 0);
      }
    }
  }
  // an reduce: 8 staging threads (t&7 = 0..7) share each row
  #pragma unroll
  for (int mask = 1; mask <= 4; mask <<= 1) {
    #pragma unroll
    for (int p = 0; p < 4; ++p) dp[p] += __shfl_xor(dp[p], mask);
  }
  if ((t & 7) == 0) {
    #pragma unroll
    for (int p = 0; p < 4; ++p) {
      int m = row0 + srow + 32 * p;
      if (m < M) anv[m] = dp[p];
    }
  }
  // Swapped-operand C/D mapping: lane l, reg q of acc[i][j] holds
  // C[row0+32wv+16i+(l&15)][16j+4*(l>>4)+q] -> 4 consecutive cols.
  int cq = lane >> 4, rl = lane & 15;
  #pragma unroll
  for (int j = 0; j < 16; ++j) {
    int col = 16 * j + 4 * cq;
    float4 b4 = *(const float4*)(bias + col);
    #pragma unroll
    for (int i = 0; i < 2; ++i) {
      int row = row0 + 32 * wv + 16 * i + rl;
      if (row < M) {
        ushort4v p;
        p[0] = f2bf(acc[i][j][0] + b4.x);
        p[1] = f2bf(acc[i][j][1] + b4.y);
        p[2] = f2bf(acc[i][j][2] + b4.z);
        p[3] = f2bf(acc[i][j][3] + b4.w);
        *(ushort4v*)(dstC + (long)row * 256 + col) = p;
      }
    }
  }
}

// K3: alpha softmax (reads an_s_m/an_t_m from K2 — row-m indexed).
__global__ __launch_bounds__(256) void alpha_k(
    const float* __restrict__ an_s_m, const float* __restrict__ an_t_m,
    const int* __restrict__ tid_arr, const float* __restrict__ consts,
    const float* __restrict__ ba, float* __restrict__ alpha, int Ns) {
  int g = blockIdx.x * 256 + threadIdx.x;
  int s = g >> 1, b = g & 1;
  if (s >= Ns) return;
  float base = an_s_m[2 * s + b] + consts[0] + consts[1] + ba[0];
  float ex[DEG];
  float den = 0.f;
  #pragma unroll
  for (int j = 0; j < DEG; ++j) {
    int t = tid_arr[s * DEG + j];
    float sc = base + an_t_m[2 * t + b];
    sc = sc > 0.f ? sc : SLOPE * sc;
    sc = fminf(2.f, fmaxf(-2.f, sc));
    float ev = __expf(sc);
    ex[j] = ev;
    den += ev;
  }
  float inv = 1.f / den;
  #pragma unroll
  for (int j = 0; j < DEG; ++j) alpha[(long)(s * DEG + j) * B2 + b] = ex[j] * inv;
}

// K4: ONE wave per source s covering both batch rows; pure store (no RMW).
// sproj/out are use-once streams -> nontemporal (protect reused vals in L2).
__global__ __launch_bounds__(256) void aggregate_k(
    const unsigned short* __restrict__ sproj, const unsigned short* __restrict__ vals,
    const float* __restrict__ alpha, const int* __restrict__ tid_arr,
    float* __restrict__ out, int Ns) {
  int s = blockIdx.x * 4 + (threadIdx.x >> 6);
  int lane = threadIdx.x & 63;
  if (s >= Ns) return;
  int f = tid_arr[s * DEG + (lane & 15)];   // edge id (reference quirk)
  int b = lane >> 5;
  float al = alpha[(long)f * B2 + b];       // alpha for (j=lane&15, b)
  int t2 = tid_arr[f];                      // value row = tid[tid[e]]
  ushort8 sp = __builtin_nontemporal_load(
      (const ushort8*)(sproj + (long)s * 512 + lane * 8));
  float acc[8];
  #pragma unroll
  for (int k = 0; k < 8; ++k) acc[k] = bf2f(sp[k]);
  #pragma unroll
  for (int j = 0; j < DEG; ++j) {
    int rr = __shfl(t2, j);
    float aj = __shfl(al, (lane & 32) + j);  // b-matched alpha for edge j
    ushort8 v = *(const ushort8*)(vals + (long)rr * 512 + lane * 8);
    #pragma unroll
    for (int k = 0; k < 8; ++k) acc[k] += aj * bf2f(v[k]);
  }
  long ob = (long)s * 512 + lane * 8;
  f32x4 p0, p1;
  p0[0] = acc[0]; p0[1] = acc[1]; p0[2] = acc[2]; p0[3] = acc[3];
  p1[0] = acc[4]; p1[1] = acc[5]; p1[2] = acc[6]; p1[3] = acc[7];
  __builtin_nontemporal_store(p0, (f32x4*)(out + ob));
  __builtin_nontemporal_store(p1, (f32x4*)(out + ob + 4));
}

extern "C" void kernel_launch(void* const* d_in, const int* in_sizes, int n_in,
                              void* d_out, int out_size, void* d_ws, size_t ws_size,
                              hipStream_t stream) {
  const float* nodes = (const float*)d_in[0];
  const float* Ws = (const float*)d_in[1];
  const float* bs = (const float*)d_in[2];
  const float* Wt = (const float*)d_in[3];
  const float* bt = (const float*)d_in[4];
  const float* Wv = (const float*)d_in[5];
  const float* bv = (const float*)d_in[6];
  const float* Wa = (const float*)d_in[7];
  const float* ba = (const float*)d_in[8];
  const int* usrc = (const int*)d_in[9];
  const int* utgt = (const int*)d_in[10];
  const int* tidp = (const int*)d_in[12];
  int Ns = in_sizes[9], Nt = in_sizes[10];
  int NsB = Ns * B2, NtB = Nt * B2;

  unsigned short* WsT = (unsigned short*)d_ws;             // 65536
  unsigned short* WvT = WsT + 65536;                       // 65536
  unsigned short* vals_bf = WvT + 65536;                   // NtB*256
  unsigned short* sproj_bf = vals_bf + (size_t)NtB * 256;  // NsB*256
  float* fbase = (float*)(sproj_bf + (size_t)NsB * 256);
  float* an_s_m = fbase;                                   // NsB
  float* an_t_m = an_s_m + NsB;                            // NtB
  float* ws_comb = an_t_m + NtB;                           // 256
  float* wt_comb = ws_comb + 256;                          // 256
  float* consts = wt_comb + 256;                           // 2 (pad 16)
  float* alpha = consts + 16;                              // E*B2
  float* out = (float*)d_out;

  prep_w_k<<<161, 256, 0, stream>>>(Ws, Wt, Wv, Wa, bs, bt,
                                    WsT, WvT, ws_comb, wt_comb, consts);
  int maxM = NsB > NtB ? NsB : NtB;
  gemm_mfma_k<<<dim3((maxM + 127) / 128, 1, 2), 256, 0, stream>>>(
      nodes, usrc, utgt, WsT, WvT, bs, bv, ws_comb, wt_comb,
      sproj_bf, vals_bf, an_s_m, an_t_m, NsB, NtB);
  alpha_k<<<(NsB + 255) / 256, 256, 0, stream>>>(
      an_s_m, an_t_m, tidp, consts, ba, alpha, Ns);
  aggregate_k<<<(Ns + 3) / 4, 256, 0, stream>>>(
      sproj_bf, vals_bf, alpha, tidp, out, Ns);
}

// Round 11
// 135.750 us; speedup vs baseline: 15.0258x; 1.0790x over previous
//
#include <hip/hip_runtime.h>

#define B2 2
#define DEG 16
#define SLOPE 0.2f

typedef __attribute__((ext_vector_type(8))) short short8;
typedef __attribute__((ext_vector_type(8))) unsigned short ushort8;
typedef __attribute__((ext_vector_type(4))) unsigned short ushort4v;
typedef __attribute__((ext_vector_type(4))) float f32x4;

__device__ inline unsigned short f2bf(float f) {
  union { float f; unsigned u; } v; v.f = f;
  unsigned r = v.u + 0x7fff + ((v.u >> 16) & 1);   // RNE
  return (unsigned short)(r >> 16);
}
__device__ inline float bf2f(unsigned short u) {
  union { unsigned u; float f; } c; c.u = ((unsigned)u) << 16;
  return c.f;
}
__device__ inline ushort8 f2bf8(float4 lo, float4 hi) {
  ushort8 r;
  r[0] = f2bf(lo.x); r[1] = f2bf(lo.y); r[2] = f2bf(lo.z); r[3] = f2bf(lo.w);
  r[4] = f2bf(hi.x); r[5] = f2bf(hi.y); r[6] = f2bf(hi.z); r[7] = f2bf(hi.w);
  return r;
}
__device__ inline float dot8(float4 a0, float4 a1, float4 c0, float4 c1) {
  return a0.x * c0.x + a0.y * c0.y + a0.z * c0.z + a0.w * c0.w +
         a1.x * c1.x + a1.y * c1.y + a1.z * c1.z + a1.w * c1.w;
}

__device__ inline float wave_dot256(const float* __restrict__ a,
                                    const float* __restrict__ b, int lane) {
  float4 x = *(const float4*)(a + lane * 4);
  float4 y = *(const float4*)(b + lane * 4);
  float v = x.x * y.x + x.y * y.y + x.z * y.z + x.w * y.w;
  #pragma unroll
  for (int off = 32; off; off >>= 1) v += __shfl_down(v, off);
  return v;
}

// K1: blocks 0..31 transpose Ws/Wv [K][N]f32 -> [N][K]bf16;
// blocks 32..160: ws_comb/wt_comb row-dots + consts. (R2-proven.)
__global__ __launch_bounds__(256) void prep_w_k(
    const float* __restrict__ Ws, const float* __restrict__ Wt,
    const float* __restrict__ Wv, const float* __restrict__ Wa,
    const float* __restrict__ bs, const float* __restrict__ bt,
    unsigned short* __restrict__ WsT, unsigned short* __restrict__ WvT,
    float* __restrict__ ws_comb, float* __restrict__ wt_comb,
    float* __restrict__ consts) {
  int bx = blockIdx.x;
  if (bx < 32) {
    const float* src = (bx & 16) ? Wv : Ws;
    unsigned short* dst = (bx & 16) ? WvT : WsT;
    int rc = bx & 15;
    int r0 = (rc >> 2) * 64, c0 = (rc & 3) * 64;
    __shared__ float tile[64][65];
    int tr = threadIdx.x >> 6, tc = threadIdx.x & 63;
    #pragma unroll
    for (int i = 0; i < 16; ++i) {
      int r = tr * 16 + i;
      tile[r][tc] = src[(long)(r0 + r) * 256 + c0 + tc];
    }
    __syncthreads();
    #pragma unroll
    for (int i = 0; i < 16; ++i) {
      int r = tr * 16 + i;
      dst[(long)(c0 + r) * 256 + r0 + tc] = f2bf(tile[tc][r]);
    }
  } else {
    int wave = (bx - 32) * 4 + (threadIdx.x >> 6);
    int lane = threadIdx.x & 63;
    if (wave >= 514) return;
    const float *vec, *wa;
    float* dst;
    if (wave < 256)       { vec = Ws + (long)wave * 256;         wa = Wa;       dst = ws_comb + wave; }
    else if (wave < 512)  { vec = Wt + (long)(wave - 256) * 256; wa = Wa + 256; dst = wt_comb + (wave - 256); }
    else if (wave == 512) { vec = bs; wa = Wa;       dst = consts; }
    else                  { vec = bt; wa = Wa + 256; dst = consts + 1; }
    float v = wave_dot256(vec, wa, lane);
    if (lane == 0) *dst = v;
  }
}

// K2: MFMA GEMM, 64x256 tile (BM=64 restores grid parallelism: 626 blocks,
// ~3 blocks/CU at 45KB LDS; BN=256 keeps A staged ONCE). A straight from
// f32 nodes (in-register RNE f2bf during staging — D2 pass stays deleted);
// staging threads also dot A-strips with ws_comb/wt_comb -> an_s_m/an_t_m.
// Operand-swapped MFMA: lane holds 4 consecutive output cols -> 8B C stores.
__global__ __launch_bounds__(256, 3) void gemm_mfma_k(
    const float* __restrict__ nodesf,
    const int* __restrict__ usrc, const int* __restrict__ utgt,
    const unsigned short* __restrict__ WsT, const unsigned short* __restrict__ WvT,
    const float* __restrict__ bs, const float* __restrict__ bv,
    const float* __restrict__ ws_comb, const float* __restrict__ wt_comb,
    unsigned short* __restrict__ sproj_bf, unsigned short* __restrict__ vals_bf,
    float* __restrict__ an_s_m, float* __restrict__ an_t_m,
    int Ms, int Mt) {
  bool second = blockIdx.z != 0;
  const int* idx = second ? utgt : usrc;
  const unsigned short* WT = second ? WvT : WsT;
  const float* bias = second ? bv : bs;
  const float* comb = second ? wt_comb : ws_comb;
  unsigned short* dstC = second ? vals_bf : sproj_bf;
  float* anv = second ? an_t_m : an_s_m;
  int M = second ? Mt : Ms;
  int row0 = blockIdx.x * 64;
  if (row0 >= M) return;

  constexpr int LDT = 72;
  __shared__ unsigned short As[64 * LDT];    // 9.2 KB
  __shared__ unsigned short Bs[256 * LDT];   // 36.9 KB
  int t = threadIdx.x;
  int wv = t >> 6, lane = t & 63;
  int arow = t >> 2;           // 0..63 (staging row)
  int acol = (t & 3) * 16;     // 0,16,32,48 (k-offset within K-tile)
  int m = row0 + arow;
  int mc = m < M ? m : M - 1;
  const float* apf = nodesf + ((long)idx[mc >> 1] * B2 + (mc & 1)) * 256 + acol;
  const unsigned short* bp[4];
  #pragma unroll
  for (int q = 0; q < 4; ++q)
    bp[q] = WT + (long)(arow + 64 * q) * 256 + acol;

  f32x4 acc[16];
  #pragma unroll
  for (int j = 0; j < 16; ++j) acc[j] = (f32x4)(0.f);

  ushort8 avbf[2], bvv[4][2];
  float dp = 0.f;
  // prologue k0 = 0: A f32 load + comb dot + bf16 convert; B bf16 load
  {
    float4 c0 = *(const float4*)(comb + acol);
    float4 c1 = *(const float4*)(comb + acol + 4);
    float4 a0 = *(const float4*)(apf);
    float4 a1 = *(const float4*)(apf + 4);
    float4 a2 = *(const float4*)(apf + 8);
    float4 a3 = *(const float4*)(apf + 12);
    float4 c2 = *(const float4*)(comb + acol + 8);
    float4 c3 = *(const float4*)(comb + acol + 12);
    dp += dot8(a0, a1, c0, c1) + dot8(a2, a3, c2, c3);
    avbf[0] = f2bf8(a0, a1);
    avbf[1] = f2bf8(a2, a3);
    #pragma unroll
    for (int q = 0; q < 4; ++q) {
      bvv[q][0] = *(const ushort8*)(bp[q]);
      bvv[q][1] = *(const ushort8*)(bp[q] + 8);
    }
  }

  #pragma unroll
  for (int k0 = 0; k0 < 256; k0 += 64) {
    __syncthreads();             // previous tile fully consumed
    *(ushort8*)&As[arow * LDT + acol] = avbf[0];
    *(ushort8*)&As[arow * LDT + acol + 8] = avbf[1];
    #pragma unroll
    for (int q = 0; q < 4; ++q) {
      *(ushort8*)&Bs[(arow + 64 * q) * LDT + acol] = bvv[q][0];
      *(ushort8*)&Bs[(arow + 64 * q) * LDT + acol + 8] = bvv[q][1];
    }
    __syncthreads();
    // prefetch next K-tile under the MFMAs (+ comb dot + convert)
    if (k0 < 192) {
      int kn = k0 + 64;
      float4 c0 = *(const float4*)(comb + kn + acol);
      float4 c1 = *(const float4*)(comb + kn + acol + 4);
      float4 a0 = *(const float4*)(apf + kn);
      float4 a1 = *(const float4*)(apf + kn + 4);
      float4 a2 = *(const float4*)(apf + kn + 8);
      float4 a3 = *(const float4*)(apf + kn + 12);
      float4 c2 = *(const float4*)(comb + kn + acol + 8);
      float4 c3 = *(const float4*)(comb + kn + acol + 12);
      dp += dot8(a0, a1, c0, c1) + dot8(a2, a3, c2, c3);
      avbf[0] = f2bf8(a0, a1);
      avbf[1] = f2bf8(a2, a3);
      #pragma unroll
      for (int q = 0; q < 4; ++q) {
        bvv[q][0] = *(const ushort8*)(bp[q] + kn);
        bvv[q][1] = *(const ushort8*)(bp[q] + kn + 8);
      }
    }
    int rl = lane & 15;
    #pragma unroll
    for (int ks = 0; ks < 64; ks += 32) {
      int ko = ks + (lane >> 4) * 8;
      short8 af = *(const short8*)&As[(16 * wv + rl) * LDT + ko];
      #pragma unroll
      for (int j = 0; j < 16; ++j) {
        short8 bf = *(const short8*)&Bs[(16 * j + rl) * LDT + ko];
        acc[j] = __builtin_amdgcn_mfma_f32_16x16x32_bf16(bf, af, acc[j], 0, 0, 0);
      }
    }
  }
  // an reduce across the 4 staging threads of each row
  dp += __shfl_xor(dp, 1);
  dp += __shfl_xor(dp, 2);
  if ((t & 3) == 0 && m < M) anv[m] = dp;

  // Swapped-operand C/D mapping: lane l, reg q of acc[j] holds
  // C[row0+16wv+(l&15)][16j+4*(l>>4)+q] -> 4 consecutive cols.
  int cq = lane >> 4, rl = lane & 15;
  int row = row0 + 16 * wv + rl;
  if (row < M) {
    #pragma unroll
    for (int j = 0; j < 16; ++j) {
      int col = 16 * j + 4 * cq;
      float4 b4 = *(const float4*)(bias + col);
      ushort4v p;
      p[0] = f2bf(acc[j][0] + b4.x);
      p[1] = f2bf(acc[j][1] + b4.y);
      p[2] = f2bf(acc[j][2] + b4.z);
      p[3] = f2bf(acc[j][3] + b4.w);
      *(ushort4v*)(dstC + (long)row * 256 + col) = p;
    }
  }
}

// K3: alpha softmax (reads an_s_m/an_t_m from K2 — row-m indexed).
__global__ __launch_bounds__(256) void alpha_k(
    const float* __restrict__ an_s_m, const float* __restrict__ an_t_m,
    const int* __restrict__ tid_arr, const float* __restrict__ consts,
    const float* __restrict__ ba, float* __restrict__ alpha, int Ns) {
  int g = blockIdx.x * 256 + threadIdx.x;
  int s = g >> 1, b = g & 1;
  if (s >= Ns) return;
  float base = an_s_m[2 * s + b] + consts[0] + consts[1] + ba[0];
  float ex[DEG];
  float den = 0.f;
  #pragma unroll
  for (int j = 0; j < DEG; ++j) {
    int t = tid_arr[s * DEG + j];
    float sc = base + an_t_m[2 * t + b];
    sc = sc > 0.f ? sc : SLOPE * sc;
    sc = fminf(2.f, fmaxf(-2.f, sc));
    float ev = __expf(sc);
    ex[j] = ev;
    den += ev;
  }
  float inv = 1.f / den;
  #pragma unroll
  for (int j = 0; j < DEG; ++j) alpha[(long)(s * DEG + j) * B2 + b] = ex[j] * inv;
}

// K4: ONE wave per source s covering both batch rows; pure store (no RMW).
// sproj/out are use-once streams -> nontemporal (protect reused vals in L2).
__global__ __launch_bounds__(256) void aggregate_k(
    const unsigned short* __restrict__ sproj, const unsigned short* __restrict__ vals,
    const float* __restrict__ alpha, const int* __restrict__ tid_arr,
    float* __restrict__ out, int Ns) {
  int s = blockIdx.x * 4 + (threadIdx.x >> 6);
  int lane = threadIdx.x & 63;
  if (s >= Ns) return;
  int f = tid_arr[s * DEG + (lane & 15)];   // edge id (reference quirk)
  int b = lane >> 5;
  float al = alpha[(long)f * B2 + b];       // alpha for (j=lane&15, b)
  int t2 = tid_arr[f];                      // value row = tid[tid[e]]
  ushort8 sp = __builtin_nontemporal_load(
      (const ushort8*)(sproj + (long)s * 512 + lane * 8));
  float acc[8];
  #pragma unroll
  for (int k = 0; k < 8; ++k) acc[k] = bf2f(sp[k]);
  #pragma unroll
  for (int j = 0; j < DEG; ++j) {
    int rr = __shfl(t2, j);
    float aj = __shfl(al, (lane & 32) + j);  // b-matched alpha for edge j
    ushort8 v = *(const ushort8*)(vals + (long)rr * 512 + lane * 8);
    #pragma unroll
    for (int k = 0; k < 8; ++k) acc[k] += aj * bf2f(v[k]);
  }
  long ob = (long)s * 512 + lane * 8;
  f32x4 p0, p1;
  p0[0] = acc[0]; p0[1] = acc[1]; p0[2] = acc[2]; p0[3] = acc[3];
  p1[0] = acc[4]; p1[1] = acc[5]; p1[2] = acc[6]; p1[3] = acc[7];
  __builtin_nontemporal_store(p0, (f32x4*)(out + ob));
  __builtin_nontemporal_store(p1, (f32x4*)(out + ob + 4));
}

extern "C" void kernel_launch(void* const* d_in, const int* in_sizes, int n_in,
                              void* d_out, int out_size, void* d_ws, size_t ws_size,
                              hipStream_t stream) {
  const float* nodes = (const float*)d_in[0];
  const float* Ws = (const float*)d_in[1];
  const float* bs = (const float*)d_in[2];
  const float* Wt = (const float*)d_in[3];
  const float* bt = (const float*)d_in[4];
  const float* Wv = (const float*)d_in[5];
  const float* bv = (const float*)d_in[6];
  const float* Wa = (const float*)d_in[7];
  const float* ba = (const float*)d_in[8];
  const int* usrc = (const int*)d_in[9];
  const int* utgt = (const int*)d_in[10];
  const int* tidp = (const int*)d_in[12];
  int Ns = in_sizes[9], Nt = in_sizes[10];
  int NsB = Ns * B2, NtB = Nt * B2;

  unsigned short* WsT = (unsigned short*)d_ws;             // 65536
  unsigned short* WvT = WsT + 65536;                       // 65536
  unsigned short* vals_bf = WvT + 65536;                   // NtB*256
  unsigned short* sproj_bf = vals_bf + (size_t)NtB * 256;  // NsB*256
  float* fbase = (float*)(sproj_bf + (size_t)NsB * 256);
  float* an_s_m = fbase;                                   // NsB
  float* an_t_m = an_s_m + NsB;                            // NtB
  float* ws_comb = an_t_m + NtB;                           // 256
  float* wt_comb = ws_comb + 256;                          // 256
  float* consts = wt_comb + 256;                           // 2 (pad 16)
  float* alpha = consts + 16;                              // E*B2
  float* out = (float*)d_out;

  prep_w_k<<<161, 256, 0, stream>>>(Ws, Wt, Wv, Wa, bs, bt,
                                    WsT, WvT, ws_comb, wt_comb, consts);
  int maxM = NsB > NtB ? NsB : NtB;
  gemm_mfma_k<<<dim3((maxM + 63) / 64, 1, 2), 256, 0, stream>>>(
      nodes, usrc, utgt, WsT, WvT, bs, bv, ws_comb, wt_comb,
      sproj_bf, vals_bf, an_s_m, an_t_m, NsB, NtB);
  alpha_k<<<(NsB + 255) / 256, 256, 0, stream>>>(
      an_s_m, an_t_m, tidp, consts, ba, alpha, Ns);
  aggregate_k<<<(Ns + 3) / 4, 256, 0, stream>>>(
      sproj_bf, vals_bf, alpha, tidp, out, Ns);
}